// Round 3
// baseline (31529.620 us; speedup 1.0000x reference)
//
#include <hip/hip_runtime.h>

#define TT 20
#define HH 20
#define CC 2      // coords per thread: amortizes LDS weight reads across CC FMAs
#define BLK 256

__device__ __forceinline__ float fast_sigmoid(float x) {
    float e = __builtin_amdgcn_exp2f(-1.44269504f * x);
    return __builtin_amdgcn_rcpf(1.0f + e);
}

__device__ __forceinline__ float fast_tanh(float x) {
    float e = __builtin_amdgcn_exp2f(2.88539008f * x);
    return 1.0f - 2.0f * __builtin_amdgcn_rcpf(e + 1.0f);
}

// State (h,c,hn for CC coords ~ 120 floats) MUST stay in VGPRs: cap no lower
// than 2 waves/SIMD (256 VGPRs). R2's (256,4) hint forced 64 VGPRs -> scratch
// spills -> 1.8 GB HBM traffic. Weights live in LDS, read as uniform-address
// float4 broadcasts (rows are 80 B = 5 aligned b128, zero bank conflicts).
__global__ __launch_bounds__(BLK, 2)
void coord_lstm_kernel(const float* __restrict__ grads,
                       const float* __restrict__ w_ih,
                       const float* __restrict__ w_hh,
                       const float* __restrict__ b_ih,
                       const float* __restrict__ b_hh,
                       const float* __restrict__ w_fc,
                       const float* __restrict__ b_fc,
                       float* __restrict__ out,
                       int N)
{
    __shared__ float s_whh[4 * HH * HH];   // [gate_row 0..79][j 0..19]
    __shared__ float s_wih[4 * HH];
    __shared__ float s_bias[4 * HH];
    __shared__ float s_wfc[HH];
    __shared__ float s_bfc;

    for (int i = threadIdx.x; i < 4 * HH * HH; i += BLK) s_whh[i] = w_hh[i];
    if (threadIdx.x < 4 * HH) {
        s_wih[threadIdx.x]  = w_ih[threadIdx.x];
        s_bias[threadIdx.x] = b_ih[threadIdx.x] + b_hh[threadIdx.x];
    } else if (threadIdx.x >= 128 && threadIdx.x < 128 + HH) {
        s_wfc[threadIdx.x - 128] = w_fc[threadIdx.x - 128];
    } else if (threadIdx.x == 255) {
        s_bfc = b_fc[0];
    }
    __syncthreads();

    const int n0 = blockIdx.x * (BLK * CC) + threadIdx.x;

    float h[CC][HH], c[CC][HH];
    #pragma unroll
    for (int k = 0; k < CC; ++k)
        #pragma unroll
        for (int u = 0; u < HH; ++u) { h[k][u] = 0.0f; c[k][u] = 0.0f; }

    #pragma unroll 1   // keep t-loop rolled: protect I$
    for (int t = 0; t < TT; ++t) {
        float x[CC];
        #pragma unroll
        for (int k = 0; k < CC; ++k) {
            const int n = n0 + k * BLK;
            x[k] = (n < N) ? grads[(size_t)t * N + n] : 0.0f;
        }

        float hn[CC][HH];
        #pragma unroll
        for (int u = 0; u < HH; ++u) {
            float ai[CC], af[CC], ag[CC], ao[CC];
            const float bi = s_bias[u         ], wi_s = s_wih[u         ];
            const float bf = s_bias[u +     HH], wf_s = s_wih[u +     HH];
            const float bg = s_bias[u + 2 * HH], wg_s = s_wih[u + 2 * HH];
            const float bo = s_bias[u + 3 * HH], wo_s = s_wih[u + 3 * HH];
            #pragma unroll
            for (int k = 0; k < CC; ++k) {
                ai[k] = fmaf(x[k], wi_s, bi);
                af[k] = fmaf(x[k], wf_s, bf);
                ag[k] = fmaf(x[k], wg_s, bg);
                ao[k] = fmaf(x[k], wo_s, bo);
            }
            #pragma unroll
            for (int j4 = 0; j4 < HH / 4; ++j4) {
                const float4 wi = *(const float4*)&s_whh[(u         ) * HH + 4 * j4];
                const float4 wf = *(const float4*)&s_whh[(u +     HH) * HH + 4 * j4];
                const float4 wg = *(const float4*)&s_whh[(u + 2 * HH) * HH + 4 * j4];
                const float4 wo = *(const float4*)&s_whh[(u + 3 * HH) * HH + 4 * j4];
                #pragma unroll
                for (int k = 0; k < CC; ++k) {
                    const float h0 = h[k][4 * j4 + 0];
                    const float h1 = h[k][4 * j4 + 1];
                    const float h2 = h[k][4 * j4 + 2];
                    const float h3 = h[k][4 * j4 + 3];
                    ai[k] = fmaf(h0, wi.x, fmaf(h1, wi.y, fmaf(h2, wi.z, fmaf(h3, wi.w, ai[k]))));
                    af[k] = fmaf(h0, wf.x, fmaf(h1, wf.y, fmaf(h2, wf.z, fmaf(h3, wf.w, af[k]))));
                    ag[k] = fmaf(h0, wg.x, fmaf(h1, wg.y, fmaf(h2, wg.z, fmaf(h3, wg.w, ag[k]))));
                    ao[k] = fmaf(h0, wo.x, fmaf(h1, wo.y, fmaf(h2, wo.z, fmaf(h3, wo.w, ao[k]))));
                }
            }
            #pragma unroll
            for (int k = 0; k < CC; ++k) {
                const float cn = fast_sigmoid(af[k]) * c[k][u]
                               + fast_sigmoid(ai[k]) * fast_tanh(ag[k]);
                c[k][u]  = cn;
                hn[k][u] = fast_sigmoid(ao[k]) * fast_tanh(cn);
            }
        }

        #pragma unroll
        for (int k = 0; k < CC; ++k) {
            float o = s_bfc;
            #pragma unroll
            for (int u = 0; u < HH; ++u) {
                o += hn[k][u] * s_wfc[u];
                h[k][u] = hn[k][u];
            }
            const int n = n0 + k * BLK;
            if (n < N) out[(size_t)t * N + n] = o;
        }
    }
}

extern "C" void kernel_launch(void* const* d_in, const int* in_sizes, int n_in,
                              void* d_out, int out_size, void* d_ws, size_t ws_size,
                              hipStream_t stream) {
    const float* grads = (const float*)d_in[0];
    const float* w_ih  = (const float*)d_in[1];
    const float* w_hh  = (const float*)d_in[2];
    const float* b_ih  = (const float*)d_in[3];
    const float* b_hh  = (const float*)d_in[4];
    const float* w_fc  = (const float*)d_in[5];
    const float* b_fc  = (const float*)d_in[6];
    float* out = (float*)d_out;

    const int N = in_sizes[0] / TT;   // grads is (T, N)
    const int per_block = BLK * CC;
    const int grid = (N + per_block - 1) / per_block;
    coord_lstm_kernel<<<grid, BLK, 0, stream>>>(grads, w_ih, w_hh, b_ih, b_hh,
                                                w_fc, b_fc, out, N);
}

// Round 4
// 2750.694 us; speedup vs baseline: 11.4624x; 11.4624x over previous
//
#include <hip/hip_runtime.h>

#define TT 20
#define HH 20

__device__ __forceinline__ float fast_sigmoid(float x) {
    // 1/(1+exp(-x)) = rcp(1 + exp2(-x*log2(e)))
    float e = __builtin_amdgcn_exp2f(-1.44269504f * x);
    return __builtin_amdgcn_rcpf(1.0f + e);
}

__device__ __forceinline__ float fast_tanh(float x) {
    // tanh(x) = 1 - 2/(exp(2x)+1); saturates to +/-1 without NaN at |x| large
    float e = __builtin_amdgcn_exp2f(2.88539008f * x);
    return 1.0f - 2.0f * __builtin_amdgcn_rcpf(e + 1.0f);
}

// Weights are wave-uniform: all weight/bias indices are compile-time constants
// off uniform bases, pointers const __restrict__ -> AMDGPU backend scalarizes
// them to s_load_* through the constant cache (R2 confirmed: SGPR=112).
// Every inner op is then v_fmac_f32 v, s, v — no LDS, no VMEM for weights.
//
// CRITICAL: no min-occupancy arg in __launch_bounds__. This kernel's live
// state (h[20], c[20], hn[20], gate temps ~ 90+ floats) must stay in VGPRs;
// caps of 64 (R2) and 128 (R3) both forced scratch spills -> GBs of HBM
// traffic and 6-30 ms. Plain (256) gave 236 VGPRs, zero spills (R1).
__global__ __launch_bounds__(256)
void coord_lstm_kernel(const float* __restrict__ grads,
                       const float* __restrict__ w_ih,
                       const float* __restrict__ w_hh,
                       const float* __restrict__ b_ih,
                       const float* __restrict__ b_hh,
                       const float* __restrict__ w_fc,
                       const float* __restrict__ b_fc,
                       float* __restrict__ out,
                       int N)
{
    const int n = blockIdx.x * 256 + threadIdx.x;
    if (n >= N) return;

    float h[HH], c[HH];
    #pragma unroll
    for (int u = 0; u < HH; ++u) { h[u] = 0.0f; c[u] = 0.0f; }

    float x = grads[n];   // t = 0

    #pragma unroll 1      // keep t-loop rolled: body ~2.2k VALU ops, protect I$
    for (int t = 0; t < TT; ++t) {
        // prefetch next step's input; dependence distance ~ full step body
        const int tn = (t + 1 < TT) ? t + 1 : t;
        const float x_next = grads[(size_t)tn * N + n];

        float hn[HH];
        #pragma unroll
        for (int u = 0; u < HH; ++u) {
            float ai = fmaf(x, w_ih[u         ], b_ih[u         ] + b_hh[u         ]);
            float af = fmaf(x, w_ih[u +     HH], b_ih[u +     HH] + b_hh[u +     HH]);
            float ag = fmaf(x, w_ih[u + 2 * HH], b_ih[u + 2 * HH] + b_hh[u + 2 * HH]);
            float ao = fmaf(x, w_ih[u + 3 * HH], b_ih[u + 3 * HH] + b_hh[u + 3 * HH]);
            #pragma unroll
            for (int j = 0; j < HH; ++j) {
                const float hj = h[j];
                ai = fmaf(hj, w_hh[(u         ) * HH + j], ai);
                af = fmaf(hj, w_hh[(u +     HH) * HH + j], af);
                ag = fmaf(hj, w_hh[(u + 2 * HH) * HH + j], ag);
                ao = fmaf(hj, w_hh[(u + 3 * HH) * HH + j], ao);
            }
            const float cn = fast_sigmoid(af) * c[u] + fast_sigmoid(ai) * fast_tanh(ag);
            c[u] = cn;
            hn[u] = fast_sigmoid(ao) * fast_tanh(cn);
        }
        float o = b_fc[0];
        #pragma unroll
        for (int u = 0; u < HH; ++u) {
            o = fmaf(hn[u], w_fc[u], o);
            h[u] = hn[u];
        }
        out[(size_t)t * N + n] = o;
        x = x_next;
    }
}

extern "C" void kernel_launch(void* const* d_in, const int* in_sizes, int n_in,
                              void* d_out, int out_size, void* d_ws, size_t ws_size,
                              hipStream_t stream) {
    const float* grads = (const float*)d_in[0];
    const float* w_ih  = (const float*)d_in[1];
    const float* w_hh  = (const float*)d_in[2];
    const float* b_ih  = (const float*)d_in[3];
    const float* b_hh  = (const float*)d_in[4];
    const float* w_fc  = (const float*)d_in[5];
    const float* b_fc  = (const float*)d_in[6];
    float* out = (float*)d_out;

    const int N = in_sizes[0] / TT;   // grads is (T, N)
    const int grid = (N + 255) / 256;
    coord_lstm_kernel<<<grid, 256, 0, stream>>>(grads, w_ih, w_hh, b_ih, b_hh,
                                                w_fc, b_fc, out, N);
}

// Round 5
// 672.331 us; speedup vs baseline: 46.8960x; 4.0913x over previous
//
#include <hip/hip_runtime.h>

#define TT 20
#define HH 20

typedef float f32x4 __attribute__((ext_vector_type(4)));
typedef short bf16x8 __attribute__((ext_vector_type(8)));

__device__ __forceinline__ short f2bf(float f) {
    // round-to-nearest-even f32 -> bf16 (no NaN handling needed: finite data)
    unsigned u = __float_as_uint(f);
    unsigned r = (u + 0x7fffu + ((u >> 16) & 1u)) >> 16;
    return (short)r;
}
__device__ __forceinline__ float bf2f(short s) {
    return __uint_as_float(((unsigned)(unsigned short)s) << 16);
}

__device__ __forceinline__ float fast_sigmoid(float x) {
    float e = __builtin_amdgcn_exp2f(-1.44269504f * x);
    return __builtin_amdgcn_rcpf(1.0f + e);
}
__device__ __forceinline__ float fast_tanh(float x) {
    float e = __builtin_amdgcn_exp2f(2.88539008f * x);
    return 1.0f - 2.0f * __builtin_amdgcn_rcpf(e + 1.0f);
}

// Build B fragments (hi/lo split) from lane-local state.
// Lane (g = lane>>4, n = lane&15) supplies B[k = 8g+e][col n] for frag b
// (coord = base + 16b + n). K-slot permutation: k=8g+e -> e<5: unit 4e+g
// (exactly the units this lane owns: u = 4t+g); e=7: g0 -> x, g1 -> 1.0.
__device__ __forceinline__ void build_B(const float (&hn)[5][4], const float (&xv)[4],
                                        int g, bf16x8 (&Bhi)[4], bf16x8 (&Blo)[4])
{
    #pragma unroll
    for (int b = 0; b < 4; ++b) {
        bf16x8 bh, bl;
        #pragma unroll
        for (int e = 0; e < 5; ++e) {
            const float v = hn[e][b];
            const short hi = f2bf(v);
            bh[e] = hi;
            bl[e] = f2bf(v - bf2f(hi));
        }
        bh[5] = 0; bh[6] = 0; bl[5] = 0; bl[6] = 0;
        const short xhi = f2bf(xv[b]);
        const short xlo = f2bf(xv[b] - bf2f(xhi));
        bh[7] = (g == 0) ? xhi : ((g == 1) ? (short)0x3F80 : (short)0);
        bl[7] = (g == 0) ? xlo : (short)0;
        Bhi[b] = bh; Blo[b] = bl;
    }
}

// One wave = 64 coords for all 20 steps. Weights live permanently in VGPRs as
// MFMA A-fragments (built once). Per step: 72 mfma_f32_16x16x32_bf16
// (hi*hi + hi*lo + lo*hi split precision), lane-local nonlinearity, zero LDS,
// zero cross-lane, zero per-step weight loads.
__global__ __launch_bounds__(256)
void coord_lstm_mfma(const float* __restrict__ grads,
                     const float* __restrict__ w_ih,
                     const float* __restrict__ w_hh,
                     const float* __restrict__ b_ih,
                     const float* __restrict__ b_hh,
                     const float* __restrict__ w_fc,
                     const float* __restrict__ b_fc,
                     float* __restrict__ out,
                     int N)
{
    const int lane = threadIdx.x & 63;
    const int g = lane >> 4;
    const int n = lane & 15;
    const long long base = ((long long)blockIdx.x * 4 + (threadIdx.x >> 6)) * 64;
    if (base >= N) return;

    // ---- A fragments, built once: rows packed r = 4u + gate (tiles 0..4),
    // tile 5 row 80 = output projection (w_fc, b_fc). Lane supplies
    // A[16*tA + n][k = 8g + e].
    bf16x8 Ahi[6], Alo[6];
    #pragma unroll
    for (int tA = 0; tA < 6; ++tA) {
        bf16x8 ah, al;
        #pragma unroll
        for (int e = 0; e < 8; ++e) {
            float v = 0.0f;
            if (tA < 5) {
                const int r = 16 * tA + n;
                const int u_r = r >> 2;       // unit
                const int gate = r & 3;       // 0=i 1=f 2=g 3=o
                const int row_w = gate * HH + u_r;
                if (e < 5)       v = w_hh[row_w * HH + (4 * e + g)];
                else if (e == 7) v = (g == 0) ? w_ih[row_w]
                                   : (g == 1) ? (b_ih[row_w] + b_hh[row_w]) : 0.0f;
            } else {
                if (e < 5)       v = (n == 0) ? w_fc[4 * e + g] : 0.0f;
                else if (e == 7) v = (g == 1 && n == 0) ? b_fc[0] : 0.0f;
            }
            const short hi = f2bf(v);
            ah[e] = hi;
            al[e] = f2bf(v - bf2f(hi));
        }
        Ahi[tA] = ah; Alo[tA] = al;
    }

    const f32x4 zero4 = {0.0f, 0.0f, 0.0f, 0.0f};

    // lane-local state: c/h for unit u = 4t + g, coord = base + 16b + n
    float c[5][4], hn[5][4];
    #pragma unroll
    for (int t5 = 0; t5 < 5; ++t5)
        #pragma unroll
        for (int b = 0; b < 4; ++b) { c[t5][b] = 0.0f; hn[t5][b] = 0.0f; }

    float xv[4];
    #pragma unroll
    for (int b = 0; b < 4; ++b) {
        long long cc = base + 16 * b + n;
        if (cc >= N) cc = N - 1;
        xv[b] = grads[cc];                 // x(t=0)
    }

    bf16x8 Bhi[4], Blo[4];
    build_B(hn, xv, g, Bhi, Blo);          // B = [h(-1)=0 ; x(0); 1]

    #pragma unroll 1
    for (int t = 0; t < TT; ++t) {
        // prefetch x(t+1)
        const int tn = (t + 1 < TT) ? t + 1 : t;
        float xn[4];
        #pragma unroll
        for (int b = 0; b < 4; ++b) {
            long long cc = base + 16 * b + n;
            if (cc >= N) cc = N - 1;
            xn[b] = grads[(size_t)tn * N + cc];
        }

        // gates = W * [h(t-1); x(t); 1]  (5 row-tiles x 4 col-frags x 3 split)
        f32x4 acc[5][4];
        #pragma unroll
        for (int tile = 0; tile < 5; ++tile) {
            #pragma unroll
            for (int b = 0; b < 4; ++b) {
                f32x4 a = __builtin_amdgcn_mfma_f32_16x16x32_bf16(Ahi[tile], Bhi[b], zero4, 0, 0, 0);
                a = __builtin_amdgcn_mfma_f32_16x16x32_bf16(Ahi[tile], Blo[b], a, 0, 0, 0);
                a = __builtin_amdgcn_mfma_f32_16x16x32_bf16(Alo[tile], Bhi[b], a, 0, 0, 0);
                acc[tile][b] = a;
            }
        }

        // nonlinearity: lane holds (i,f,g,o) in regs 0..3 for unit 4*tile+g
        #pragma unroll
        for (int tile = 0; tile < 5; ++tile) {
            #pragma unroll
            for (int b = 0; b < 4; ++b) {
                const float iv = acc[tile][b][0];
                const float fv = acc[tile][b][1];
                const float gv = acc[tile][b][2];
                const float ov = acc[tile][b][3];
                const float cn = fast_sigmoid(fv) * c[tile][b]
                               + fast_sigmoid(iv) * fast_tanh(gv);
                c[tile][b]  = cn;
                hn[tile][b] = fast_sigmoid(ov) * fast_tanh(cn);
            }
        }

        // B_new = [h(t); x(t+1); 1] — feeds out(t) (x-slot unused there) and gates(t+1)
        build_B(hn, xn, g, Bhi, Blo);

        // out(t) = w_fc . h(t) + b_fc  (tile 5, row 80 -> lanes g==0, reg 0)
        #pragma unroll
        for (int b = 0; b < 4; ++b) {
            f32x4 o = __builtin_amdgcn_mfma_f32_16x16x32_bf16(Ahi[5], Bhi[b], zero4, 0, 0, 0);
            o = __builtin_amdgcn_mfma_f32_16x16x32_bf16(Ahi[5], Blo[b], o, 0, 0, 0);
            o = __builtin_amdgcn_mfma_f32_16x16x32_bf16(Alo[5], Bhi[b], o, 0, 0, 0);
            if (g == 0) {
                const long long cc = base + 16 * b + n;
                if (cc < N) out[(size_t)t * N + cc] = o[0];
            }
        }
    }
}

extern "C" void kernel_launch(void* const* d_in, const int* in_sizes, int n_in,
                              void* d_out, int out_size, void* d_ws, size_t ws_size,
                              hipStream_t stream) {
    const float* grads = (const float*)d_in[0];
    const float* w_ih  = (const float*)d_in[1];
    const float* w_hh  = (const float*)d_in[2];
    const float* b_ih  = (const float*)d_in[3];
    const float* b_hh  = (const float*)d_in[4];
    const float* w_fc  = (const float*)d_in[5];
    const float* b_fc  = (const float*)d_in[6];
    float* out = (float*)d_out;

    const int N = in_sizes[0] / TT;            // grads is (T, N)
    const long long waves = ((long long)N + 63) / 64;
    const int blocks = (int)((waves + 3) / 4); // 4 waves per 256-thread block
    coord_lstm_mfma<<<blocks, 256, 0, stream>>>(grads, w_ih, w_hh, b_ih, b_hh,
                                                w_fc, b_fc, out, N);
}

// Round 6
// 526.822 us; speedup vs baseline: 59.8487x; 1.2762x over previous
//
#include <hip/hip_runtime.h>

#define TT 20
#define HH 20

typedef float f32x4 __attribute__((ext_vector_type(4)));
typedef short bf16x8 __attribute__((ext_vector_type(8)));
typedef unsigned uint4v __attribute__((ext_vector_type(4)));

__device__ __forceinline__ short f2bf(float f) {
    unsigned u = __float_as_uint(f);
    unsigned r = (u + 0x7fffu + ((u >> 16) & 1u)) >> 16;
    return (short)r;
}
__device__ __forceinline__ float bf2f(short s) {
    return __uint_as_float(((unsigned)(unsigned short)s) << 16);
}

// packed f32x2 -> bf16x2 (RTNE), a -> low half, b -> high half
__device__ __forceinline__ unsigned pk_bf16(float a, float b) {
    unsigned r;
    asm("v_cvt_pk_bf16_f32 %0, %1, %2" : "=v"(r) : "v"(a), "v"(b));
    return r;
}
__device__ __forceinline__ float lo_half(unsigned u) {   // bf2f(element 0)
    return __uint_as_float(u << 16);
}
__device__ __forceinline__ float hi_half(unsigned u) {   // bf2f(element 1)
    return __uint_as_float(u & 0xffff0000u);
}

// Build B fragments (hi + residual-lo) from lane-local state via v_cvt_pk.
// Lane (g = lane>>4, n = lane&15): B[k = 8g+e][col] ; e<5 -> h[unit 4e+g],
// e=7 -> x (g0) / 1.0 (g1) / 0 ; e=5,6 pad.
__device__ __forceinline__ void build_B(const float (&hn)[5][4], const float (&xv)[4],
                                        int g, bf16x8 (&Bhi)[4], bf16x8 (&Blo)[4])
{
    #pragma unroll
    for (int b = 0; b < 4; ++b) {
        const float h0 = hn[0][b], h1 = hn[1][b], h2 = hn[2][b],
                    h3 = hn[3][b], h4 = hn[4][b];
        const float s7 = (g == 0) ? xv[b] : ((g == 1) ? 1.0f : 0.0f);
        const unsigned u0 = pk_bf16(h0, h1);
        const unsigned u1 = pk_bf16(h2, h3);
        const unsigned u2 = pk_bf16(h4, 0.0f);
        const unsigned u3 = pk_bf16(0.0f, s7);
        const float l0 = h0 - lo_half(u0);
        const float l1 = h1 - hi_half(u0);
        const float l2 = h2 - lo_half(u1);
        const float l3 = h3 - hi_half(u1);
        const float l4 = h4 - lo_half(u2);
        const float l7 = (g == 0) ? (xv[b] - hi_half(u3)) : 0.0f;
        const unsigned v0 = pk_bf16(l0, l1);
        const unsigned v1 = pk_bf16(l2, l3);
        const unsigned v2 = pk_bf16(l4, 0.0f);
        const unsigned v3 = pk_bf16(0.0f, l7);
        uint4v uh; uh[0] = u0; uh[1] = u1; uh[2] = u2; uh[3] = u3;
        uint4v ul; ul[0] = v0; ul[1] = v1; ul[2] = v2; ul[3] = v3;
        Bhi[b] = __builtin_bit_cast(bf16x8, uh);
        Blo[b] = __builtin_bit_cast(bf16x8, ul);
    }
}

// One wave = 64 coords, weights permanently in VGPRs as MFMA A-fragments.
// i/f/o gate rows pre-scaled by -log2(e), g rows by +2*log2(e) so MFMA output
// feeds v_exp_f32 (exp2) directly. Nonlinearity uses merged-rcp forms:
//   cn = [c*(1+ei)(1+eg) + (eg-1)(1+ef)] * rcp((1+ef)(1+ei)(1+eg))
//   hn = (ec-1) * rcp((1+eo)(1+ec)),  ec = exp2(2*log2e*cn)
// -> 5 exp + 2 rcp per unit (was 5+5). Per-tile acc keeps only 16 live
// accumulator regs and interleaves MFMA with VALU.
__global__ __launch_bounds__(256)
void coord_lstm_mfma(const float* __restrict__ grads,
                     const float* __restrict__ w_ih,
                     const float* __restrict__ w_hh,
                     const float* __restrict__ b_ih,
                     const float* __restrict__ b_hh,
                     const float* __restrict__ w_fc,
                     const float* __restrict__ b_fc,
                     float* __restrict__ out,
                     int N)
{
    const int lane = threadIdx.x & 63;
    const int g = lane >> 4;
    const int n = lane & 15;
    const long long base = ((long long)blockIdx.x * 4 + (threadIdx.x >> 6)) * 64;
    if (base >= N) return;

    const float LOG2E  = 1.4426950408889634f;
    const float TLOG2E = 2.8853900817779268f;

    // ---- A fragments, built once. Tiles 0..4: row r=16*tA+n -> unit r>>2,
    // gate r&3 (0=i 1=f 2=g 3=o), source row gate*HH+unit, pre-scaled.
    // Tile 5: output projection (w_fc row, b_fc in the 1-column), unscaled.
    bf16x8 Ahi[6], Alo[6];
    #pragma unroll
    for (int tA = 0; tA < 6; ++tA) {
        bf16x8 ah, al;
        #pragma unroll
        for (int e = 0; e < 8; ++e) {
            float v = 0.0f;
            if (tA < 5) {
                const int r = 16 * tA + n;
                const int u_r = r >> 2;
                const int gate = r & 3;
                const float scale = (gate == 2) ? TLOG2E : -LOG2E;
                const int row_w = gate * HH + u_r;
                if (e < 5)       v = scale * w_hh[row_w * HH + (4 * e + g)];
                else if (e == 7) v = (g == 0) ? scale * w_ih[row_w]
                                   : (g == 1) ? scale * (b_ih[row_w] + b_hh[row_w]) : 0.0f;
            } else {
                if (e < 5)       v = (n == 0) ? w_fc[4 * e + g] : 0.0f;
                else if (e == 7) v = (g == 1 && n == 0) ? b_fc[0] : 0.0f;
            }
            const short hi = f2bf(v);
            ah[e] = hi;
            al[e] = f2bf(v - bf2f(hi));
        }
        Ahi[tA] = ah; Alo[tA] = al;
    }

    const f32x4 zero4 = {0.0f, 0.0f, 0.0f, 0.0f};

    // clamped coordinates + store guards, hoisted out of the t-loop
    long long cc[4]; bool wr[4];
    #pragma unroll
    for (int b = 0; b < 4; ++b) {
        long long c0 = base + 16 * b + n;
        wr[b] = (c0 < N);
        cc[b] = wr[b] ? c0 : (long long)(N - 1);
    }

    float c[5][4], hn[5][4];
    #pragma unroll
    for (int t5 = 0; t5 < 5; ++t5)
        #pragma unroll
        for (int b = 0; b < 4; ++b) { c[t5][b] = 0.0f; hn[t5][b] = 0.0f; }

    float xv[4];
    #pragma unroll
    for (int b = 0; b < 4; ++b) xv[b] = grads[cc[b]];   // x(t=0)

    bf16x8 Bhi[4], Blo[4];
    build_B(hn, xv, g, Bhi, Blo);                        // [h(-1)=0 ; x(0); 1]

    #pragma unroll 1
    for (int t = 0; t < TT; ++t) {
        const int tn = (t + 1 < TT) ? t + 1 : t;
        float xn[4];
        #pragma unroll
        for (int b = 0; b < 4; ++b) xn[b] = grads[(size_t)tn * N + cc[b]];

        // per tile: 12 MFMA then lane-local nonlinearity (i,f,g,o in regs 0..3)
        #pragma unroll
        for (int tile = 0; tile < 5; ++tile) {
            f32x4 acc[4];
            #pragma unroll
            for (int b = 0; b < 4; ++b) {
                f32x4 a = __builtin_amdgcn_mfma_f32_16x16x32_bf16(Ahi[tile], Bhi[b], zero4, 0, 0, 0);
                a = __builtin_amdgcn_mfma_f32_16x16x32_bf16(Ahi[tile], Blo[b], a, 0, 0, 0);
                a = __builtin_amdgcn_mfma_f32_16x16x32_bf16(Alo[tile], Bhi[b], a, 0, 0, 0);
                acc[b] = a;
            }
            #pragma unroll
            for (int b = 0; b < 4; ++b) {
                const float ei = __builtin_amdgcn_exp2f(acc[b][0]);   // -log2e * a_i
                const float ef = __builtin_amdgcn_exp2f(acc[b][1]);
                const float eg = __builtin_amdgcn_exp2f(acc[b][2]);   // +2log2e * a_g
                const float eo = __builtin_amdgcn_exp2f(acc[b][3]);
                const float pi = 1.0f + ei, pf = 1.0f + ef;
                const float pg = 1.0f + eg, po = 1.0f + eo;
                const float pig = pi * pg;
                const float r3  = __builtin_amdgcn_rcpf(pig * pf);
                const float cn  = fmaf(c[tile][b], pig, (eg - 1.0f) * pf) * r3;
                c[tile][b] = cn;
                const float ec = __builtin_amdgcn_exp2f(TLOG2E * cn);
                const float pc = 1.0f + ec;
                hn[tile][b] = (ec - 1.0f) * __builtin_amdgcn_rcpf(po * pc);
            }
        }

        // B_new = [h(t); x(t+1); 1]
        build_B(hn, xn, g, Bhi, Blo);

        // out(t) = w_fc . h(t) + b_fc   (tile 5 -> lanes g==0, reg 0)
        #pragma unroll
        for (int b = 0; b < 4; ++b) {
            f32x4 o = __builtin_amdgcn_mfma_f32_16x16x32_bf16(Ahi[5], Bhi[b], zero4, 0, 0, 0);
            o = __builtin_amdgcn_mfma_f32_16x16x32_bf16(Ahi[5], Blo[b], o, 0, 0, 0);
            o = __builtin_amdgcn_mfma_f32_16x16x32_bf16(Alo[5], Bhi[b], o, 0, 0, 0);
            if (g == 0 && wr[b]) out[(size_t)t * N + cc[b]] = o[0];
        }
    }
}

extern "C" void kernel_launch(void* const* d_in, const int* in_sizes, int n_in,
                              void* d_out, int out_size, void* d_ws, size_t ws_size,
                              hipStream_t stream) {
    const float* grads = (const float*)d_in[0];
    const float* w_ih  = (const float*)d_in[1];
    const float* w_hh  = (const float*)d_in[2];
    const float* b_ih  = (const float*)d_in[3];
    const float* b_hh  = (const float*)d_in[4];
    const float* w_fc  = (const float*)d_in[5];
    const float* b_fc  = (const float*)d_in[6];
    float* out = (float*)d_out;

    const int N = in_sizes[0] / TT;            // grads is (T, N)
    const long long waves = ((long long)N + 63) / 64;
    const int blocks = (int)((waves + 3) / 4); // 4 waves per 256-thread block
    coord_lstm_mfma<<<blocks, 256, 0, stream>>>(grads, w_ih, w_hh, b_ih, b_hh,
                                                w_fc, b_fc, out, N);
}